// Round 1
// 454.630 us; speedup vs baseline: 1.0437x; 1.0437x over previous
//
#include <hip/hip_runtime.h>

#define T     8192
#define DH    64
#define TMASK 8191
#define SCALE 0.044194173824159216f   // (h*dh)^-0.5 = 512^-0.5
#define NEGF  -3.402823466e38f

typedef __attribute__((ext_vector_type(8))) short bf16x8;
typedef __attribute__((ext_vector_type(4))) float f32x4;

static __device__ __forceinline__ unsigned short f2bf(float f) {
  unsigned int u = __float_as_uint(f);
  u += 0x7fffu + ((u >> 16) & 1u);      // round-to-nearest-even
  return (unsigned short)(u >> 16);
}

// ---------------------------------------------------------------------------
// Kernel A1: per-segment (bucket) sums of rotated k. grid = 64 bh * 8 = 512.
// float4 per thread (4 channels of one segment); rows summed sequentially
// 0..63 -> accumulation order bitwise-identical to the previous version.
// Per wave: 4 segments x 16 c4-lanes -> each load instr = 4 full 256B rows.
// ---------------------------------------------------------------------------
__global__ void __launch_bounds__(256) seg_sums_kernel(
    const float* __restrict__ k, float* __restrict__ segs) {
  int bid = blockIdx.x;
  int bhi = bid >> 3;
  int ch  = bid & 7;
  int hd  = bhi & 7;
  bool rot = hd >= 4;
  int tid = threadIdx.x;
  int lane = tid & 63;
  int wv   = tid >> 6;
  int sg   = ch * 16 + wv * 4 + (lane >> 4);
  int c4   = (lane & 15) << 2;
  const float* kb = k + (size_t)bhi * T * DH;
  int t0 = sg * 64;
  float s0 = 0.f, s1 = 0.f, s2 = 0.f, s3 = 0.f;
#pragma unroll 8
  for (int s = 0; s < 64; ++s) {
    int t  = t0 + s;
    int st = rot ? ((t + 63) & TMASK) : t;
    float4 x = *(const float4*)(kb + (size_t)st * DH + c4);
    s0 += x.x; s1 += x.y; s2 += x.z; s3 += x.w;
  }
  *(float4*)(segs + ((size_t)bhi * 128 + sg) * 64 + c4) =
      make_float4(s0, s1, s2, s3);
}

// ---------------------------------------------------------------------------
// Kernel A2: routing (unchanged algorithm; d-loop unrolled x4 for MLP).
// grid = 64 bh * 8 = 512.
// ---------------------------------------------------------------------------
__global__ void __launch_bounds__(256) route_kernel(
    const float* __restrict__ k, const float* __restrict__ sortW,
    const float* __restrict__ segs,
    int* __restrict__ routeIdx, float* __restrict__ routeP) {
  __shared__ float sSeg[128 * 64];   // 32 KB
  __shared__ float sX[16 * 128];     // 8 KB: [row][0:64]=cumavg, [64:128]=first
  int bid = blockIdx.x;
  int bhi = bid >> 3;
  int u0  = (bid & 7) * 16;
  int hd  = bhi & 7;
  bool rot = hd >= 4;
  int tid = threadIdx.x;
  const float* kb = k + (size_t)bhi * T * DH;
  const float* sg = segs + (size_t)bhi * 128 * 64;

  // stage segs (8192 floats, coalesced)
#pragma unroll
  for (int it = 0; it < 8; ++it) {
    int f4 = (it * 256 + tid) * 4;
    *(float4*)(sSeg + f4) = *(const float4*)(sg + f4);
  }
  // stage bucket-start k rows for our 16 rows
  {
    int r = tid >> 4, c4 = (tid & 15) << 2;
    int t = (u0 + r) * 64;
    int st = rot ? ((t + 63) & TMASK) : t;
    *(float4*)(sX + r * 128 + 64 + c4) = *(const float4*)(kb + (size_t)st * DH + c4);
  }
  __syncthreads();
  // exclusive prefix (serial over u, per-channel order matches round-1) + cumavg
  {
    int r = tid >> 4, c4 = (tid & 15) << 2;
    int u = u0 + r;
    float4 run = make_float4(0.f, 0.f, 0.f, 0.f);
    for (int uu = 0; uu < u; ++uu) {
      float4 sv = *(const float4*)(sSeg + uu * 64 + c4);
      run.x += sv.x; run.y += sv.y; run.z += sv.z; run.w += sv.w;
    }
    float4 first = *(const float4*)(sX + r * 128 + 64 + c4);
    float den = (float)(u * 64 + 1);
    float4 cum = make_float4((run.x + first.x) / den, (run.y + first.y) / den,
                             (run.z + first.z) / den, (run.w + first.w) / den);
    *(float4*)(sX + r * 128 + c4) = cum;
  }
  __syncthreads();

  // matmul: row u = u0+ty, cols c = tx+16j (col 128 always masked, skipped)
  int ty = tid >> 4, tx = tid & 15;
  int u = u0 + ty;
  const float* Wh = sortW + (size_t)hd * 128 * 129;
  float z[8] = {0.f, 0.f, 0.f, 0.f, 0.f, 0.f, 0.f, 0.f};
#pragma unroll 4
  for (int d = 0; d < 128; ++d) {
    float xv = sX[ty * 128 + d];
    const float* wr = Wh + (size_t)d * 129 + tx;
#pragma unroll
    for (int j = 0; j < 8; ++j) z[j] = fmaf(xv, wr[j * 16], z[j]);
  }
  // leaky_relu, causal softmax over c<=u, argmax over c<u
  float l[8];
  float mx = NEGF;
#pragma unroll
  for (int j = 0; j < 8; ++j) {
    int c = tx + 16 * j;
    float lv = z[j] >= 0.f ? z[j] : 0.01f * z[j];
    l[j] = lv;
    if (c <= u) mx = fmaxf(mx, lv);
  }
  for (int off = 1; off < 16; off <<= 1) mx = fmaxf(mx, __shfl_xor(mx, off));
  float se = 0.f;
#pragma unroll
  for (int j = 0; j < 8; ++j) {
    int c = tx + 16 * j;
    if (c <= u) se += __expf(l[j] - mx);
  }
  for (int off = 1; off < 16; off <<= 1) se += __shfl_xor(se, off);
  float bv = NEGF; int bi = 0x7fffffff;
#pragma unroll
  for (int j = 0; j < 8; ++j) {
    int c = tx + 16 * j;
    if (c < u && (l[j] > bv || (l[j] == bv && c < bi))) { bv = l[j]; bi = c; }
  }
  for (int off = 1; off < 16; off <<= 1) {
    float ov = __shfl_xor(bv, off); int oi = __shfl_xor(bi, off);
    if (ov > bv || (ov == bv && oi < bi)) { bv = ov; bi = oi; }
  }
  if (tx == 0) {
    if (u == 0) { routeIdx[bhi * 128] = 0; routeP[bhi * 128] = 0.f; }
    else {
      routeIdx[bhi * 128 + u] = bi;
      routeP[bhi * 128 + u]   = __expf(bv - mx) / se;
    }
  }
}

// ---------------------------------------------------------------------------
// Kernel B: MFMA attention. grid = 8192 blocks, 256 threads (4 waves).
// v2 changes vs previous round:
//   - Q fragments loaded straight to registers (sQ removed) -> LDS 34816 B
//     -> 4 blocks/CU (__launch_bounds__(256,4)), occupancy 32% -> ~43%.
//   - sVt: [64][128] bf16 with 16B-chunk XOR swizzle (chunk ^= row&15);
//     written via register 4x4 micro-tile transpose (coalesced full-row
//     float4 loads, ds_write_b64) -> PV b128 reads conflict-free.
//   - sP written pair-packed (bf16 + shfl_xor(1) + b32 store on even lanes).
//   - XCD-aware bijective blockIdx swizzle (8192 % 8 == 0).
// LDS layout (bytes):
//   sK  bf16 [128][72]  off 0      (18432)
//   sVt bf16 [64][128]  off 18432  (16384, swizzled)
//   sP  bf16 [64][136]  off 0      (17408, aliases dead sK)
// ---------------------------------------------------------------------------
__global__ void __launch_bounds__(256, 4) attn_kernel(
    const float* __restrict__ q, const float* __restrict__ k,
    const float* __restrict__ v,
    const float* __restrict__ nullk, const float* __restrict__ nullv,
    const int* __restrict__ routeIdx, const float* __restrict__ routeP,
    float* __restrict__ out) {
  __shared__ __align__(16) unsigned short smem[17408];  // 34816 B
  unsigned short* sK  = smem;           // [128][72]
  unsigned short* sVt = smem + 9216;    // [64][128] swizzled transpose
  unsigned short* sP  = smem;           // [64][136] alias over sK

  const int bid0 = blockIdx.x;
  const int bid  = ((bid0 & 7) << 10) | (bid0 >> 3);  // XCD swizzle (bijective)
  const int u   = bid & 127;
  const int bhi = bid >> 7;
  const int hd  = bhi & 7;
  const bool rot = hd >= 4;
  const int tid = threadIdx.x;
  const float* qb = q + (size_t)bhi * T * DH;
  const float* kb = k + (size_t)bhi * T * DH;
  const float* vb = v + (size_t)bhi * T * DH;
  float* ob = out + (size_t)bhi * T * DH;
  const int   ridx = routeIdx[bhi * 128 + u];
  const float p    = routeP[bhi * 128 + u];
  const float* nkh = nullk + hd * DH;
  const float* nvh = nullv + hd * DH;

  const int lane = tid & 63;
  const int w    = tid >> 6;
  const int col  = lane & 15;
  const int quad = lane >> 4;
  const int kofs = quad * 8;
  const int mrow = w * 16 + col;   // A-operand row (this wave's 16-row tile)

  // ---- Q fragments: global -> registers (scaled) ----
  bf16x8 aq0, aq1;
  {
    int t  = u * 64 + mrow;
    int st = rot ? ((t + 63) & TMASK) : t;
    const float* qr = qb + (size_t)st * DH + kofs;
    float4 a0 = *(const float4*)(qr + 0);
    float4 a1 = *(const float4*)(qr + 4);
    float4 a2 = *(const float4*)(qr + 32);
    float4 a3 = *(const float4*)(qr + 36);
    aq0[0] = (short)f2bf(a0.x * SCALE); aq0[1] = (short)f2bf(a0.y * SCALE);
    aq0[2] = (short)f2bf(a0.z * SCALE); aq0[3] = (short)f2bf(a0.w * SCALE);
    aq0[4] = (short)f2bf(a1.x * SCALE); aq0[5] = (short)f2bf(a1.y * SCALE);
    aq0[6] = (short)f2bf(a1.z * SCALE); aq0[7] = (short)f2bf(a1.w * SCALE);
    aq1[0] = (short)f2bf(a2.x * SCALE); aq1[1] = (short)f2bf(a2.y * SCALE);
    aq1[2] = (short)f2bf(a2.z * SCALE); aq1[3] = (short)f2bf(a2.w * SCALE);
    aq1[4] = (short)f2bf(a3.x * SCALE); aq1[5] = (short)f2bf(a3.y * SCALE);
    aq1[6] = (short)f2bf(a3.z * SCALE); aq1[7] = (short)f2bf(a3.w * SCALE);
  }

  // ---- K2 (rows 0..63 routed*p, 64..127 causal) ----
#pragma unroll
  for (int it = 0; it < 8; ++it) {
    int flat = it * 256 + tid;
    int row = flat >> 4, c4 = (flat & 15) << 2;
    float4 kv;
    if (row < 64) {
      if (ridx == 0) kv = *(const float4*)(nkh + c4);
      else {
        int t = (ridx - 1) * 64 + row;
        int st = rot ? ((t + 63) & TMASK) : t;
        kv = *(const float4*)(kb + (size_t)st * DH + c4);
      }
      kv.x *= p; kv.y *= p; kv.z *= p; kv.w *= p;
    } else {
      int t = u * 64 + (row - 64);
      int st = rot ? ((t + 63) & TMASK) : t;
      kv = *(const float4*)(kb + (size_t)st * DH + c4);
    }
    ushort4 o4;
    o4.x = f2bf(kv.x); o4.y = f2bf(kv.y); o4.z = f2bf(kv.z); o4.w = f2bf(kv.w);
    *(ushort4*)(sK + row * 72 + c4) = o4;
  }

  // ---- V2: register 4x4 micro-tile transpose into swizzled sVt ----
  // element V2[tok][n] lives at shorts: n*128 + ((tok>>3 ^ (n&15))<<3) + (tok&7)
#pragma unroll
  for (int it = 0; it < 2; ++it) {
    int flat = it * 256 + tid;       // 0..511
    int tok4 = flat >> 4;            // 0..31: 4-token group
    int d4   = (flat & 15) << 2;     // dh base 0..60
    int tb   = tok4 * 4;
    float va[4][4];
    if (tb < 64) {
      if (ridx == 0) {
        float4 nv = *(const float4*)(nvh + d4);
        float n0 = nv.x * p, n1 = nv.y * p, n2 = nv.z * p, n3 = nv.w * p;
#pragma unroll
        for (int jj = 0; jj < 4; ++jj) {
          va[jj][0] = n0; va[jj][1] = n1; va[jj][2] = n2; va[jj][3] = n3;
        }
      } else {
#pragma unroll
        for (int jj = 0; jj < 4; ++jj) {
          int t = (ridx - 1) * 64 + tb + jj;
          int st = rot ? ((t + 63) & TMASK) : t;
          float4 x = *(const float4*)(vb + (size_t)st * DH + d4);
          va[jj][0] = x.x * p; va[jj][1] = x.y * p;
          va[jj][2] = x.z * p; va[jj][3] = x.w * p;
        }
      }
    } else {
#pragma unroll
      for (int jj = 0; jj < 4; ++jj) {
        int t = u * 64 + (tb - 64) + jj;
        int st = rot ? ((t + 63) & TMASK) : t;
        float4 x = *(const float4*)(vb + (size_t)st * DH + d4);
        va[jj][0] = x.x; va[jj][1] = x.y; va[jj][2] = x.z; va[jj][3] = x.w;
      }
    }
    int chunk = tok4 >> 1, ph = tok4 & 1;
#pragma unroll
    for (int dd = 0; dd < 4; ++dd) {
      int n = d4 + dd;
      ushort4 o;
      o.x = f2bf(va[0][dd]); o.y = f2bf(va[1][dd]);
      o.z = f2bf(va[2][dd]); o.w = f2bf(va[3][dd]);
      *(ushort4*)(sVt + n * 128 + ((chunk ^ (n & 15)) << 3) + (ph << 2)) = o;
    }
  }
  __syncthreads();

  // ---- S = Q . K2^T ----
  f32x4 acc[8];
#pragma unroll
  for (int j = 0; j < 8; ++j) acc[j] = (f32x4){0.f, 0.f, 0.f, 0.f};
#pragma unroll
  for (int j = 0; j < 8; ++j) {
    bf16x8 b0 = *(const bf16x8*)(sK + (j * 16 + col) * 72 + 0  + kofs);
    acc[j] = __builtin_amdgcn_mfma_f32_16x16x32_bf16(aq0, b0, acc[j], 0, 0, 0);
    bf16x8 b1 = *(const bf16x8*)(sK + (j * 16 + col) * 72 + 32 + kofs);
    acc[j] = __builtin_amdgcn_mfma_f32_16x16x32_bf16(aq1, b1, acc[j], 0, 0, 0);
  }

  // ---- mask + softmax (C-layout: row = 16w + 4*quad + reg, col = 16j + col) ----
  const bool spec = rot && (u == 127);
#pragma unroll
  for (int reg = 0; reg < 4; ++reg) {
    int r = w * 16 + quad * 4 + reg;
    float mx = -1e30f;
#pragma unroll
    for (int j = 0; j < 8; ++j) {
      int c = j * 16 + col;
      bool vis = (c < 64) || ((c - 64) <= r);
      if (spec && r >= 1 && c <= 64) vis = false;
      float val = vis ? acc[j][reg] : -1e30f;
      acc[j][reg] = val;
      mx = fmaxf(mx, val);
    }
#pragma unroll
    for (int off = 1; off < 16; off <<= 1) mx = fmaxf(mx, __shfl_xor(mx, off));
    float s = 0.f;
#pragma unroll
    for (int j = 0; j < 8; ++j) {
      float e = __expf(acc[j][reg] - mx);
      acc[j][reg] = e; s += e;
    }
#pragma unroll
    for (int off = 1; off < 16; off <<= 1) s += __shfl_xor(s, off);
    float inv = 1.f / s;
#pragma unroll
    for (int j = 0; j < 8; ++j) acc[j][reg] *= inv;
  }

  __syncthreads();   // everyone done reading sK before aliased sP writes
  // ---- P -> LDS, pair-packed b32 stores (even-col lanes) ----
#pragma unroll
  for (int j = 0; j < 8; ++j) {
#pragma unroll
    for (int reg = 0; reg < 4; ++reg) {
      unsigned int mybf = f2bf(acc[j][reg]);
      unsigned int obf  = (unsigned int)__shfl_xor((int)mybf, 1);
      if ((col & 1) == 0) {
        int r = w * 16 + quad * 4 + reg;
        *(unsigned int*)(sP + r * 136 + j * 16 + col) = mybf | (obf << 16);
      }
    }
  }
  __syncthreads();

  // ---- O = P . V2 ----
  f32x4 oacc[4];
#pragma unroll
  for (int jt = 0; jt < 4; ++jt) oacc[jt] = (f32x4){0.f, 0.f, 0.f, 0.f};
#pragma unroll
  for (int ks = 0; ks < 4; ++ks) {
    bf16x8 ap = *(const bf16x8*)(sP + mrow * 136 + ks * 32 + kofs);
#pragma unroll
    for (int jt = 0; jt < 4; ++jt) {
      int n = jt * 16 + col;
      bf16x8 bv = *(const bf16x8*)(sVt + n * 128 + (((ks * 4 + quad) ^ col) << 3));
      oacc[jt] = __builtin_amdgcn_mfma_f32_16x16x32_bf16(ap, bv, oacc[jt], 0, 0, 0);
    }
  }

  // ---- store (C-layout rows, inverse rotation) ----
#pragma unroll
  for (int reg = 0; reg < 4; ++reg) {
    int r = w * 16 + quad * 4 + reg;
    int t = u * 64 + r;
    int st = rot ? ((t + 63) & TMASK) : t;
    float* orow = ob + (size_t)st * DH;
#pragma unroll
    for (int jt = 0; jt < 4; ++jt)
      orow[jt * 16 + col] = oacc[jt][reg];
  }
}

// ---------------------------------------------------------------------------
extern "C" void kernel_launch(void* const* d_in, const int* in_sizes, int n_in,
                              void* d_out, int out_size, void* d_ws, size_t ws_size,
                              hipStream_t stream) {
  const float* q     = (const float*)d_in[0];
  const float* k     = (const float*)d_in[1];
  const float* v     = (const float*)d_in[2];
  const float* sortW = (const float*)d_in[3];
  const float* nullk = (const float*)d_in[4];
  const float* nullv = (const float*)d_in[5];
  float* out = (float*)d_out;

  float* segs     = (float*)d_ws;
  int*   routeIdx = (int*)((char*)d_ws + (size_t)64 * 128 * 64 * 4);
  float* routeP   = (float*)((char*)d_ws + (size_t)64 * 128 * 64 * 4 + 32768);

  seg_sums_kernel<<<512, 256, 0, stream>>>(k, segs);
  route_kernel<<<512, 256, 0, stream>>>(k, sortW, segs, routeIdx, routeP);
  attn_kernel<<<8192, 256, 0, stream>>>(q, k, v, nullk, nullv,
                                        routeIdx, routeP, out);
}

// Round 2
// 453.450 us; speedup vs baseline: 1.0464x; 1.0026x over previous
//
#include <hip/hip_runtime.h>

#define T     8192
#define DH    64
#define TMASK 8191
#define SCALE 0.044194173824159216f   // (h*dh)^-0.5 = 512^-0.5
#define NEGF  -3.402823466e38f

typedef __attribute__((ext_vector_type(8))) short bf16x8;
typedef __attribute__((ext_vector_type(4))) float f32x4;
typedef __attribute__((ext_vector_type(4))) unsigned int u32x4;

// Native bf16 convert: compiles to v_cvt_pk_bf16_f32 (RNE, same as manual RNE).
static __device__ __forceinline__ unsigned short f2bf(float f) {
  __bf16 h = (__bf16)f;
  return __builtin_bit_cast(unsigned short, h);
}
static __device__ __forceinline__ unsigned int pk2(float a, float b) {
  return (unsigned int)f2bf(a) | ((unsigned int)f2bf(b) << 16);
}

// ---------------------------------------------------------------------------
// Kernel A1: per-segment (bucket) sums of rotated k. grid = 64 bh * 8 = 512.
// ---------------------------------------------------------------------------
__global__ void __launch_bounds__(256) seg_sums_kernel(
    const float* __restrict__ k, float* __restrict__ segs) {
  int bid = blockIdx.x;
  int bhi = bid >> 3;
  int ch  = bid & 7;
  int hd  = bhi & 7;
  bool rot = hd >= 4;
  int tid = threadIdx.x;
  int lane = tid & 63;
  int wv   = tid >> 6;
  int sg   = ch * 16 + wv * 4 + (lane >> 4);
  int c4   = (lane & 15) << 2;
  const float* kb = k + (size_t)bhi * T * DH;
  int t0 = sg * 64;
  float s0 = 0.f, s1 = 0.f, s2 = 0.f, s3 = 0.f;
#pragma unroll 8
  for (int s = 0; s < 64; ++s) {
    int t  = t0 + s;
    int st = rot ? ((t + 63) & TMASK) : t;
    float4 x = *(const float4*)(kb + (size_t)st * DH + c4);
    s0 += x.x; s1 += x.y; s2 += x.z; s3 += x.w;
  }
  *(float4*)(segs + ((size_t)bhi * 128 + sg) * 64 + c4) =
      make_float4(s0, s1, s2, s3);
}

// ---------------------------------------------------------------------------
// Kernel A2: routing (unchanged). grid = 64 bh * 8 = 512.
// ---------------------------------------------------------------------------
__global__ void __launch_bounds__(256) route_kernel(
    const float* __restrict__ k, const float* __restrict__ sortW,
    const float* __restrict__ segs,
    int* __restrict__ routeIdx, float* __restrict__ routeP) {
  __shared__ float sSeg[128 * 64];   // 32 KB
  __shared__ float sX[16 * 128];     // 8 KB
  int bid = blockIdx.x;
  int bhi = bid >> 3;
  int u0  = (bid & 7) * 16;
  int hd  = bhi & 7;
  bool rot = hd >= 4;
  int tid = threadIdx.x;
  const float* kb = k + (size_t)bhi * T * DH;
  const float* sg = segs + (size_t)bhi * 128 * 64;

#pragma unroll
  for (int it = 0; it < 8; ++it) {
    int f4 = (it * 256 + tid) * 4;
    *(float4*)(sSeg + f4) = *(const float4*)(sg + f4);
  }
  {
    int r = tid >> 4, c4 = (tid & 15) << 2;
    int t = (u0 + r) * 64;
    int st = rot ? ((t + 63) & TMASK) : t;
    *(float4*)(sX + r * 128 + 64 + c4) = *(const float4*)(kb + (size_t)st * DH + c4);
  }
  __syncthreads();
  {
    int r = tid >> 4, c4 = (tid & 15) << 2;
    int u = u0 + r;
    float4 run = make_float4(0.f, 0.f, 0.f, 0.f);
    for (int uu = 0; uu < u; ++uu) {
      float4 sv = *(const float4*)(sSeg + uu * 64 + c4);
      run.x += sv.x; run.y += sv.y; run.z += sv.z; run.w += sv.w;
    }
    float4 first = *(const float4*)(sX + r * 128 + 64 + c4);
    float den = (float)(u * 64 + 1);
    float4 cum = make_float4((run.x + first.x) / den, (run.y + first.y) / den,
                             (run.z + first.z) / den, (run.w + first.w) / den);
    *(float4*)(sX + r * 128 + c4) = cum;
  }
  __syncthreads();

  int ty = tid >> 4, tx = tid & 15;
  int u = u0 + ty;
  const float* Wh = sortW + (size_t)hd * 128 * 129;
  float z[8] = {0.f, 0.f, 0.f, 0.f, 0.f, 0.f, 0.f, 0.f};
#pragma unroll 4
  for (int d = 0; d < 128; ++d) {
    float xv = sX[ty * 128 + d];
    const float* wr = Wh + (size_t)d * 129 + tx;
#pragma unroll
    for (int j = 0; j < 8; ++j) z[j] = fmaf(xv, wr[j * 16], z[j]);
  }
  float l[8];
  float mx = NEGF;
#pragma unroll
  for (int j = 0; j < 8; ++j) {
    int c = tx + 16 * j;
    float lv = z[j] >= 0.f ? z[j] : 0.01f * z[j];
    l[j] = lv;
    if (c <= u) mx = fmaxf(mx, lv);
  }
  for (int off = 1; off < 16; off <<= 1) mx = fmaxf(mx, __shfl_xor(mx, off));
  float se = 0.f;
#pragma unroll
  for (int j = 0; j < 8; ++j) {
    int c = tx + 16 * j;
    if (c <= u) se += __expf(l[j] - mx);
  }
  for (int off = 1; off < 16; off <<= 1) se += __shfl_xor(se, off);
  float bv = NEGF; int bi = 0x7fffffff;
#pragma unroll
  for (int j = 0; j < 8; ++j) {
    int c = tx + 16 * j;
    if (c < u && (l[j] > bv || (l[j] == bv && c < bi))) { bv = l[j]; bi = c; }
  }
  for (int off = 1; off < 16; off <<= 1) {
    float ov = __shfl_xor(bv, off); int oi = __shfl_xor(bi, off);
    if (ov > bv || (ov == bv && oi < bi)) { bv = ov; bi = oi; }
  }
  if (tx == 0) {
    if (u == 0) { routeIdx[bhi * 128] = 0; routeP[bhi * 128] = 0.f; }
    else {
      routeIdx[bhi * 128 + u] = bi;
      routeP[bhi * 128 + u]   = __expf(bv - mx) / se;
    }
  }
}

// ---------------------------------------------------------------------------
// Kernel B: MFMA attention. grid = 8192 blocks, 256 threads (4 waves).
// v3 changes:
//   - LDS 32768 B -> 5 blocks/CU (__launch_bounds__(256,5)).
//     sK  [128][64] XOR-swizzled (chunk^=row&7)  : 16384 B
//     sVt [64][128] XOR-swizzled (chunk^=n&15)   : 16384 B
//     sP  [64][128] XOR-swizzled (chunk^=r&15), aliases sK.
//     All staging writes / fragment reads derived conflict-free.
//   - Native __bf16 casts -> v_cvt_pk_bf16_f32 (replaces 3-4 ALU-op manual RNE).
//   - PV with swapped operands: O^T = mfma(Vt_frag, P_frag). Fragments read
//     identically; C-layout now gives each lane 4 consecutive out channels ->
//     4 float4 global stores (was 16 scalar).
//   - Softmax normalization deferred to the store (P unnormalized in bf16;
//     1/s fetched cross-quad via 4 shuffles + v_rcp).
//   - Mask with compile-time j branches (j<4 has no per-element select).
// ---------------------------------------------------------------------------
__global__ void __launch_bounds__(256, 5) attn_kernel(
    const float* __restrict__ q, const float* __restrict__ k,
    const float* __restrict__ v,
    const float* __restrict__ nullk, const float* __restrict__ nullv,
    const int* __restrict__ routeIdx, const float* __restrict__ routeP,
    float* __restrict__ out) {
  __shared__ __align__(16) unsigned short smem[16384];  // 32768 B
  unsigned short* sK  = smem;           // [128][64] swizzled
  unsigned short* sVt = smem + 8192;    // [64][128] swizzled transpose
  unsigned short* sP  = smem;           // [64][128] swizzled, alias sK

  const int bid0 = blockIdx.x;
  const int bid  = ((bid0 & 7) << 10) | (bid0 >> 3);  // XCD swizzle (bijective)
  const int u   = bid & 127;
  const int bhi = bid >> 7;
  const int hd  = bhi & 7;
  const bool rot = hd >= 4;
  const int tid = threadIdx.x;
  const float* qb = q + (size_t)bhi * T * DH;
  const float* kb = k + (size_t)bhi * T * DH;
  const float* vb = v + (size_t)bhi * T * DH;
  float* ob = out + (size_t)bhi * T * DH;
  const int   ridx = routeIdx[bhi * 128 + u];
  const float p    = routeP[bhi * 128 + u];
  const float* nkh = nullk + hd * DH;
  const float* nvh = nullv + hd * DH;

  const int lane = tid & 63;
  const int w    = tid >> 6;
  const int col  = lane & 15;
  const int quad = lane >> 4;
  const int kofs = quad * 8;
  const int mrow = w * 16 + col;   // this wave's q-row for fragments

  // ---- Q fragments: global -> registers (scaled) ----
  bf16x8 aq0, aq1;
  {
    int t  = u * 64 + mrow;
    int st = rot ? ((t + 63) & TMASK) : t;
    const float* qr = qb + (size_t)st * DH + kofs;
    float4 a0 = *(const float4*)(qr + 0);
    float4 a1 = *(const float4*)(qr + 4);
    float4 a2 = *(const float4*)(qr + 32);
    float4 a3 = *(const float4*)(qr + 36);
    u32x4 t0, t1;
    t0[0] = pk2(a0.x * SCALE, a0.y * SCALE);
    t0[1] = pk2(a0.z * SCALE, a0.w * SCALE);
    t0[2] = pk2(a1.x * SCALE, a1.y * SCALE);
    t0[3] = pk2(a1.z * SCALE, a1.w * SCALE);
    t1[0] = pk2(a2.x * SCALE, a2.y * SCALE);
    t1[1] = pk2(a2.z * SCALE, a2.w * SCALE);
    t1[2] = pk2(a3.x * SCALE, a3.y * SCALE);
    t1[3] = pk2(a3.z * SCALE, a3.w * SCALE);
    aq0 = __builtin_bit_cast(bf16x8, t0);
    aq1 = __builtin_bit_cast(bf16x8, t1);
  }

  // ---- K2 staging (rows 0..63 routed*p, 64..127 causal), swizzled ----
#pragma unroll
  for (int it = 0; it < 8; ++it) {
    int flat = it * 256 + tid;
    int row = flat >> 4, c4 = (flat & 15) << 2;
    float4 kv;
    if (row < 64) {
      if (ridx == 0) kv = *(const float4*)(nkh + c4);
      else {
        int t = (ridx - 1) * 64 + row;
        int st = rot ? ((t + 63) & TMASK) : t;
        kv = *(const float4*)(kb + (size_t)st * DH + c4);
      }
      kv.x *= p; kv.y *= p; kv.z *= p; kv.w *= p;
    } else {
      int t = u * 64 + (row - 64);
      int st = rot ? ((t + 63) & TMASK) : t;
      kv = *(const float4*)(kb + (size_t)st * DH + c4);
    }
    uint2 o;
    o.x = pk2(kv.x, kv.y);
    o.y = pk2(kv.z, kv.w);
    *(uint2*)(sK + row * 64 + (((c4 >> 3) ^ (row & 7)) << 3) + (c4 & 7)) = o;
  }

  // ---- V2: register 4x4 micro-tile transpose into swizzled sVt ----
  // element V2[tok][n] at short: n*128 + ((tok>>3 ^ (n&15))<<3) + (tok&7)
#pragma unroll
  for (int it = 0; it < 2; ++it) {
    int flat = it * 256 + tid;       // 0..511
    int tok4 = flat >> 4;            // 0..31: 4-token group
    int d4   = (flat & 15) << 2;     // dh base
    int tb   = tok4 * 4;
    float va[4][4];
    if (tb < 64) {
      if (ridx == 0) {
        float4 nv = *(const float4*)(nvh + d4);
        float n0 = nv.x * p, n1 = nv.y * p, n2 = nv.z * p, n3 = nv.w * p;
#pragma unroll
        for (int jj = 0; jj < 4; ++jj) {
          va[jj][0] = n0; va[jj][1] = n1; va[jj][2] = n2; va[jj][3] = n3;
        }
      } else {
#pragma unroll
        for (int jj = 0; jj < 4; ++jj) {
          int t = (ridx - 1) * 64 + tb + jj;
          int st = rot ? ((t + 63) & TMASK) : t;
          float4 x = *(const float4*)(vb + (size_t)st * DH + d4);
          va[jj][0] = x.x * p; va[jj][1] = x.y * p;
          va[jj][2] = x.z * p; va[jj][3] = x.w * p;
        }
      }
    } else {
#pragma unroll
      for (int jj = 0; jj < 4; ++jj) {
        int t = u * 64 + (tb - 64) + jj;
        int st = rot ? ((t + 63) & TMASK) : t;
        float4 x = *(const float4*)(vb + (size_t)st * DH + d4);
        va[jj][0] = x.x; va[jj][1] = x.y; va[jj][2] = x.z; va[jj][3] = x.w;
      }
    }
    int chunk = tok4 >> 1, ph = tok4 & 1;
#pragma unroll
    for (int dd = 0; dd < 4; ++dd) {
      int n = d4 + dd;
      uint2 o;
      o.x = pk2(va[0][dd], va[1][dd]);
      o.y = pk2(va[2][dd], va[3][dd]);
      *(uint2*)(sVt + n * 128 + ((chunk ^ (n & 15)) << 3) + (ph << 2)) = o;
    }
  }
  __syncthreads();

  // ---- S = Q . K2^T ----
  const int kx0 = ((quad ^ (col & 7)) << 3);        // sK slot, k-chunk = quad
  const int kx1 = (((4 + quad) ^ (col & 7)) << 3);  // sK slot, k-chunk = 4+quad
  f32x4 acc[8];
#pragma unroll
  for (int j = 0; j < 8; ++j) acc[j] = (f32x4){0.f, 0.f, 0.f, 0.f};
#pragma unroll
  for (int j = 0; j < 8; ++j) {
    int rowb = (j * 16 + col) * 64;
    bf16x8 b0 = *(const bf16x8*)(sK + rowb + kx0);
    acc[j] = __builtin_amdgcn_mfma_f32_16x16x32_bf16(aq0, b0, acc[j], 0, 0, 0);
    bf16x8 b1 = *(const bf16x8*)(sK + rowb + kx1);
    acc[j] = __builtin_amdgcn_mfma_f32_16x16x32_bf16(aq1, b1, acc[j], 0, 0, 0);
  }

  // ---- mask + softmax (C-layout: row = 16w+4q+reg, col = 16j+col) ----
  const bool spec = rot && (u == 127);
  float s4[4];
#pragma unroll
  for (int reg = 0; reg < 4; ++reg) {
    int r = w * 16 + quad * 4 + reg;
    bool killLow = spec && (r >= 1);
    float mx = -1e30f;
#pragma unroll
    for (int j = 0; j < 8; ++j) {
      float val = acc[j][reg];
      if (j < 4) {
        if (killLow) val = -1e30f;
      } else {
        int cc = (j - 4) * 16 + col;   // c - 64
        bool vis = cc <= r;
        if (j == 4) vis = vis && !(killLow && col == 0);
        if (!vis) val = -1e30f;
      }
      acc[j][reg] = val;
      mx = fmaxf(mx, val);
    }
#pragma unroll
    for (int off = 1; off < 16; off <<= 1) mx = fmaxf(mx, __shfl_xor(mx, off));
    float s = 0.f;
#pragma unroll
    for (int j = 0; j < 8; ++j) {
      float e = __expf(acc[j][reg] - mx);
      acc[j][reg] = e; s += e;
    }
#pragma unroll
    for (int off = 1; off < 16; off <<= 1) s += __shfl_xor(s, off);
    s4[reg] = s;   // normalization deferred to the output store
  }

  __syncthreads();   // all waves done reading sK before aliased sP writes
  // ---- P -> LDS (unnormalized), pair-packed b32 on even-col lanes ----
#pragma unroll
  for (int j = 0; j < 8; ++j) {
#pragma unroll
    for (int reg = 0; reg < 4; ++reg) {
      float partner = __shfl_xor(acc[j][reg], 1);
      if ((col & 1) == 0) {
        int r = w * 16 + quad * 4 + reg;
        int phys = r * 128 + ((((2 * j) + (col >> 3)) ^ (r & 15)) << 3) + (col & 7);
        *(unsigned int*)(sP + phys) = pk2(acc[j][reg], partner);
      }
    }
  }
  __syncthreads();

  // ---- O^T = V2^T . P^T via swapped operands ----
  f32x4 oacc[4];
#pragma unroll
  for (int jt = 0; jt < 4; ++jt) oacc[jt] = (f32x4){0.f, 0.f, 0.f, 0.f};
#pragma unroll
  for (int ks = 0; ks < 4; ++ks) {
    int slot = (((ks * 4 + quad) ^ col) << 3);
    bf16x8 ap = *(const bf16x8*)(sP + mrow * 128 + slot);
#pragma unroll
    for (int jt = 0; jt < 4; ++jt) {
      int n = jt * 16 + col;
      bf16x8 bv = *(const bf16x8*)(sVt + n * 128 + slot);
      oacc[jt] = __builtin_amdgcn_mfma_f32_16x16x32_bf16(bv, ap, oacc[jt], 0, 0, 0);
    }
  }

  // ---- fetch 1/s for this lane's q-row (row index = col) ----
  int srcl = (col >> 2) << 4;        // lane holding s for quad' = col>>2
  float sv0 = __shfl(s4[0], srcl);
  float sv1 = __shfl(s4[1], srcl);
  float sv2 = __shfl(s4[2], srcl);
  float sv3 = __shfl(s4[3], srcl);
  float sa = (col & 1) ? sv1 : sv0;
  float sb = (col & 1) ? sv3 : sv2;
  float invR = __builtin_amdgcn_rcpf((col & 2) ? sb : sa);

  // ---- store: lane owns q-row mrow, channels n = jt*16 + quad*4 + {0..3} ----
  {
    int t = u * 64 + mrow;
    int st = rot ? ((t + 63) & TMASK) : t;
    float* orow = ob + (size_t)st * DH + quad * 4;
#pragma unroll
    for (int jt = 0; jt < 4; ++jt) {
      float4 o4 = make_float4(oacc[jt][0] * invR, oacc[jt][1] * invR,
                              oacc[jt][2] * invR, oacc[jt][3] * invR);
      *(float4*)(orow + jt * 16) = o4;
    }
  }
}

// ---------------------------------------------------------------------------
extern "C" void kernel_launch(void* const* d_in, const int* in_sizes, int n_in,
                              void* d_out, int out_size, void* d_ws, size_t ws_size,
                              hipStream_t stream) {
  const float* q     = (const float*)d_in[0];
  const float* k     = (const float*)d_in[1];
  const float* v     = (const float*)d_in[2];
  const float* sortW = (const float*)d_in[3];
  const float* nullk = (const float*)d_in[4];
  const float* nullv = (const float*)d_in[5];
  float* out = (float*)d_out;

  float* segs     = (float*)d_ws;
  int*   routeIdx = (int*)((char*)d_ws + (size_t)64 * 128 * 64 * 4);
  float* routeP   = (float*)((char*)d_ws + (size_t)64 * 128 * 64 * 4 + 32768);

  seg_sums_kernel<<<512, 256, 0, stream>>>(k, segs);
  route_kernel<<<512, 256, 0, stream>>>(k, sortW, segs, routeIdx, routeP);
  attn_kernel<<<8192, 256, 0, stream>>>(q, k, v, nullk, nullv,
                                        routeIdx, routeP, out);
}

// Round 3
// 440.847 us; speedup vs baseline: 1.0763x; 1.0286x over previous
//
#include <hip/hip_runtime.h>

#define T     8192
#define DH    64
#define TMASK 8191
#define SCALE 0.044194173824159216f   // (h*dh)^-0.5 = 512^-0.5
#define NEGF  -3.402823466e38f

typedef __attribute__((ext_vector_type(8))) short bf16x8;
typedef __attribute__((ext_vector_type(4))) float f32x4;
typedef __attribute__((ext_vector_type(4))) unsigned int u32x4;

// Native bf16 convert: compiles to v_cvt_pk_bf16_f32 (RNE).
static __device__ __forceinline__ unsigned short f2bf(float f) {
  __bf16 h = (__bf16)f;
  return __builtin_bit_cast(unsigned short, h);
}
static __device__ __forceinline__ unsigned int pk2(float a, float b) {
  return (unsigned int)f2bf(a) | ((unsigned int)f2bf(b) << 16);
}

// ---------------------------------------------------------------------------
// Kernel A1: per-segment (bucket) sums of rotated k. grid = 64 bh * 8 = 512.
// ---------------------------------------------------------------------------
__global__ void __launch_bounds__(256) seg_sums_kernel(
    const float* __restrict__ k, float* __restrict__ segs) {
  int bid = blockIdx.x;
  int bhi = bid >> 3;
  int ch  = bid & 7;
  int hd  = bhi & 7;
  bool rot = hd >= 4;
  int tid = threadIdx.x;
  int lane = tid & 63;
  int wv   = tid >> 6;
  int sg   = ch * 16 + wv * 4 + (lane >> 4);
  int c4   = (lane & 15) << 2;
  const float* kb = k + (size_t)bhi * T * DH;
  int t0 = sg * 64;
  float s0 = 0.f, s1 = 0.f, s2 = 0.f, s3 = 0.f;
#pragma unroll 8
  for (int s = 0; s < 64; ++s) {
    int t  = t0 + s;
    int st = rot ? ((t + 63) & TMASK) : t;
    float4 x = *(const float4*)(kb + (size_t)st * DH + c4);
    s0 += x.x; s1 += x.y; s2 += x.z; s3 += x.w;
  }
  *(float4*)(segs + ((size_t)bhi * 128 + sg) * 64 + c4) =
      make_float4(s0, s1, s2, s3);
}

// ---------------------------------------------------------------------------
// Kernel A2: routing (unchanged). grid = 64 bh * 8 = 512.
// ---------------------------------------------------------------------------
__global__ void __launch_bounds__(256) route_kernel(
    const float* __restrict__ k, const float* __restrict__ sortW,
    const float* __restrict__ segs,
    int* __restrict__ routeIdx, float* __restrict__ routeP) {
  __shared__ float sSeg[128 * 64];   // 32 KB
  __shared__ float sX[16 * 128];     // 8 KB
  int bid = blockIdx.x;
  int bhi = bid >> 3;
  int u0  = (bid & 7) * 16;
  int hd  = bhi & 7;
  bool rot = hd >= 4;
  int tid = threadIdx.x;
  const float* kb = k + (size_t)bhi * T * DH;
  const float* sg = segs + (size_t)bhi * 128 * 64;

#pragma unroll
  for (int it = 0; it < 8; ++it) {
    int f4 = (it * 256 + tid) * 4;
    *(float4*)(sSeg + f4) = *(const float4*)(sg + f4);
  }
  {
    int r = tid >> 4, c4 = (tid & 15) << 2;
    int t = (u0 + r) * 64;
    int st = rot ? ((t + 63) & TMASK) : t;
    *(float4*)(sX + r * 128 + 64 + c4) = *(const float4*)(kb + (size_t)st * DH + c4);
  }
  __syncthreads();
  {
    int r = tid >> 4, c4 = (tid & 15) << 2;
    int u = u0 + r;
    float4 run = make_float4(0.f, 0.f, 0.f, 0.f);
    for (int uu = 0; uu < u; ++uu) {
      float4 sv = *(const float4*)(sSeg + uu * 64 + c4);
      run.x += sv.x; run.y += sv.y; run.z += sv.z; run.w += sv.w;
    }
    float4 first = *(const float4*)(sX + r * 128 + 64 + c4);
    float den = (float)(u * 64 + 1);
    float4 cum = make_float4((run.x + first.x) / den, (run.y + first.y) / den,
                             (run.z + first.z) / den, (run.w + first.w) / den);
    *(float4*)(sX + r * 128 + c4) = cum;
  }
  __syncthreads();

  int ty = tid >> 4, tx = tid & 15;
  int u = u0 + ty;
  const float* Wh = sortW + (size_t)hd * 128 * 129;
  float z[8] = {0.f, 0.f, 0.f, 0.f, 0.f, 0.f, 0.f, 0.f};
#pragma unroll 4
  for (int d = 0; d < 128; ++d) {
    float xv = sX[ty * 128 + d];
    const float* wr = Wh + (size_t)d * 129 + tx;
#pragma unroll
    for (int j = 0; j < 8; ++j) z[j] = fmaf(xv, wr[j * 16], z[j]);
  }
  float l[8];
  float mx = NEGF;
#pragma unroll
  for (int j = 0; j < 8; ++j) {
    int c = tx + 16 * j;
    float lv = z[j] >= 0.f ? z[j] : 0.01f * z[j];
    l[j] = lv;
    if (c <= u) mx = fmaxf(mx, lv);
  }
  for (int off = 1; off < 16; off <<= 1) mx = fmaxf(mx, __shfl_xor(mx, off));
  float se = 0.f;
#pragma unroll
  for (int j = 0; j < 8; ++j) {
    int c = tx + 16 * j;
    if (c <= u) se += __expf(l[j] - mx);
  }
  for (int off = 1; off < 16; off <<= 1) se += __shfl_xor(se, off);
  float bv = NEGF; int bi = 0x7fffffff;
#pragma unroll
  for (int j = 0; j < 8; ++j) {
    int c = tx + 16 * j;
    if (c < u && (l[j] > bv || (l[j] == bv && c < bi))) { bv = l[j]; bi = c; }
  }
  for (int off = 1; off < 16; off <<= 1) {
    float ov = __shfl_xor(bv, off); int oi = __shfl_xor(bi, off);
    if (ov > bv || (ov == bv && oi < bi)) { bv = ov; bi = oi; }
  }
  if (tx == 0) {
    if (u == 0) { routeIdx[bhi * 128] = 0; routeP[bhi * 128] = 0.f; }
    else {
      routeIdx[bhi * 128 + u] = bi;
      routeP[bhi * 128 + u]   = __expf(bv - mx) / se;
    }
  }
}

// ---------------------------------------------------------------------------
// Kernel B: MFMA attention. grid = 8192 blocks, 256 threads (4 waves).
// v4 changes vs v3 (which regressed 131->151 us):
//   - __launch_bounds__(256, 4): v3's (256,5) asked the compiler to schedule
//     for 5 blocks/CU, but occupancy counters show only 4 ever materialize;
//     result was a latency-sensitive schedule (VGPR 52->44, serialized
//     staging loads) at unchanged residency. Match the real occupancy.
//   - T14 issue-early/write-late staging: all 16 K/V float4 loads issued to
//     registers (statically indexed arrays) before any convert/ds_write ->
//     ~16 outstanding loads/thread hide L2/HBM latency under conversion VALU.
//   - Precise 1.0f/s (v3's v_rcp doubled absmax).
// LDS 32768 B: sK [128][64] swz | sVt [64][128] swz | sP [64][128] swz alias.
// ---------------------------------------------------------------------------
__global__ void __launch_bounds__(256, 4) attn_kernel(
    const float* __restrict__ q, const float* __restrict__ k,
    const float* __restrict__ v,
    const float* __restrict__ nullk, const float* __restrict__ nullv,
    const int* __restrict__ routeIdx, const float* __restrict__ routeP,
    float* __restrict__ out) {
  __shared__ __align__(16) unsigned short smem[16384];  // 32768 B
  unsigned short* sK  = smem;           // [128][64] swizzled
  unsigned short* sVt = smem + 8192;    // [64][128] swizzled transpose
  unsigned short* sP  = smem;           // [64][128] swizzled, alias sK

  const int bid0 = blockIdx.x;
  const int bid  = ((bid0 & 7) << 10) | (bid0 >> 3);  // XCD swizzle (bijective)
  const int u   = bid & 127;
  const int bhi = bid >> 7;
  const int hd  = bhi & 7;
  const bool rot = hd >= 4;
  const int tid = threadIdx.x;
  const float* qb = q + (size_t)bhi * T * DH;
  const float* kb = k + (size_t)bhi * T * DH;
  const float* vb = v + (size_t)bhi * T * DH;
  float* ob = out + (size_t)bhi * T * DH;
  const int   ridx = routeIdx[bhi * 128 + u];
  const float p    = routeP[bhi * 128 + u];
  const float* nkh = nullk + hd * DH;
  const float* nvh = nullv + hd * DH;

  const int lane = tid & 63;
  const int w    = tid >> 6;
  const int col  = lane & 15;
  const int quad = lane >> 4;
  const int kofs = quad * 8;
  const int mrow = w * 16 + col;   // this wave's q-row for fragments

  // ---- Q fragments: global -> registers (scaled) ----
  bf16x8 aq0, aq1;
  {
    int t  = u * 64 + mrow;
    int st = rot ? ((t + 63) & TMASK) : t;
    const float* qr = qb + (size_t)st * DH + kofs;
    float4 a0 = *(const float4*)(qr + 0);
    float4 a1 = *(const float4*)(qr + 4);
    float4 a2 = *(const float4*)(qr + 32);
    float4 a3 = *(const float4*)(qr + 36);
    u32x4 t0, t1;
    t0[0] = pk2(a0.x * SCALE, a0.y * SCALE);
    t0[1] = pk2(a0.z * SCALE, a0.w * SCALE);
    t0[2] = pk2(a1.x * SCALE, a1.y * SCALE);
    t0[3] = pk2(a1.z * SCALE, a1.w * SCALE);
    t1[0] = pk2(a2.x * SCALE, a2.y * SCALE);
    t1[1] = pk2(a2.z * SCALE, a2.w * SCALE);
    t1[2] = pk2(a3.x * SCALE, a3.y * SCALE);
    t1[3] = pk2(a3.z * SCALE, a3.w * SCALE);
    aq0 = __builtin_bit_cast(bf16x8, t0);
    aq1 = __builtin_bit_cast(bf16x8, t1);
  }

  // ---- T14 split: issue ALL K + V global loads before any LDS write ----
  float4 kreg[8];
#pragma unroll
  for (int it = 0; it < 8; ++it) {
    int flat = it * 256 + tid;
    int row = flat >> 4, c4 = (flat & 15) << 2;
    const float* src;
    if (row < 64) {
      if (ridx == 0) src = nkh + c4;
      else {
        int t = (ridx - 1) * 64 + row;
        int st = rot ? ((t + 63) & TMASK) : t;
        src = kb + (size_t)st * DH + c4;
      }
    } else {
      int t = u * 64 + (row - 64);
      int st = rot ? ((t + 63) & TMASK) : t;
      src = kb + (size_t)st * DH + c4;
    }
    kreg[it] = *(const float4*)src;
  }
  float4 vreg[2][4];
#pragma unroll
  for (int it = 0; it < 2; ++it) {
    int flat = it * 256 + tid;
    int tok4 = flat >> 4, d4 = (flat & 15) << 2;
    int tb   = tok4 * 4;
#pragma unroll
    for (int jj = 0; jj < 4; ++jj) {
      const float* src;
      if (tb < 64) {
        if (ridx == 0) src = nvh + d4;
        else {
          int t = (ridx - 1) * 64 + tb + jj;
          int st = rot ? ((t + 63) & TMASK) : t;
          src = vb + (size_t)st * DH + d4;
        }
      } else {
        int t = u * 64 + (tb - 64) + jj;
        int st = rot ? ((t + 63) & TMASK) : t;
        src = vb + (size_t)st * DH + d4;
      }
      vreg[it][jj] = *(const float4*)src;
    }
  }

  // ---- write K2 to swizzled sK (scale routed rows by p) ----
#pragma unroll
  for (int it = 0; it < 8; ++it) {
    int flat = it * 256 + tid;
    int row = flat >> 4, c4 = (flat & 15) << 2;
    float4 kv = kreg[it];
    if (row < 64) { kv.x *= p; kv.y *= p; kv.z *= p; kv.w *= p; }
    uint2 o;
    o.x = pk2(kv.x, kv.y);
    o.y = pk2(kv.z, kv.w);
    *(uint2*)(sK + row * 64 + (((c4 >> 3) ^ (row & 7)) << 3) + (c4 & 7)) = o;
  }

  // ---- write V2: register 4x4 micro-tile transpose into swizzled sVt ----
  // element V2[tok][n] at short: n*128 + ((tok>>3 ^ (n&15))<<3) + (tok&7)
#pragma unroll
  for (int it = 0; it < 2; ++it) {
    int flat = it * 256 + tid;
    int tok4 = flat >> 4, d4 = (flat & 15) << 2;
    int tb   = tok4 * 4;
    float va[4][4];
#pragma unroll
    for (int jj = 0; jj < 4; ++jj) {
      float4 x = vreg[it][jj];
      if (tb < 64) { x.x *= p; x.y *= p; x.z *= p; x.w *= p; }
      va[jj][0] = x.x; va[jj][1] = x.y; va[jj][2] = x.z; va[jj][3] = x.w;
    }
    int chunk = tok4 >> 1, ph = tok4 & 1;
#pragma unroll
    for (int dd = 0; dd < 4; ++dd) {
      int n = d4 + dd;
      uint2 o;
      o.x = pk2(va[0][dd], va[1][dd]);
      o.y = pk2(va[2][dd], va[3][dd]);
      *(uint2*)(sVt + n * 128 + ((chunk ^ (n & 15)) << 3) + (ph << 2)) = o;
    }
  }
  __syncthreads();

  // ---- S = Q . K2^T ----
  const int kx0 = ((quad ^ (col & 7)) << 3);        // sK slot, k-chunk = quad
  const int kx1 = (((4 + quad) ^ (col & 7)) << 3);  // sK slot, k-chunk = 4+quad
  f32x4 acc[8];
#pragma unroll
  for (int j = 0; j < 8; ++j) acc[j] = (f32x4){0.f, 0.f, 0.f, 0.f};
#pragma unroll
  for (int j = 0; j < 8; ++j) {
    int rowb = (j * 16 + col) * 64;
    bf16x8 b0 = *(const bf16x8*)(sK + rowb + kx0);
    acc[j] = __builtin_amdgcn_mfma_f32_16x16x32_bf16(aq0, b0, acc[j], 0, 0, 0);
    bf16x8 b1 = *(const bf16x8*)(sK + rowb + kx1);
    acc[j] = __builtin_amdgcn_mfma_f32_16x16x32_bf16(aq1, b1, acc[j], 0, 0, 0);
  }

  // ---- mask + softmax (C-layout: row = 16w+4q+reg, col = 16j+col) ----
  const bool spec = rot && (u == 127);
  float s4[4];
#pragma unroll
  for (int reg = 0; reg < 4; ++reg) {
    int r = w * 16 + quad * 4 + reg;
    bool killLow = spec && (r >= 1);
    float mx = -1e30f;
#pragma unroll
    for (int j = 0; j < 8; ++j) {
      float val = acc[j][reg];
      if (j < 4) {
        if (killLow) val = -1e30f;
      } else {
        int cc = (j - 4) * 16 + col;   // c - 64
        bool vis = cc <= r;
        if (j == 4) vis = vis && !(killLow && col == 0);
        if (!vis) val = -1e30f;
      }
      acc[j][reg] = val;
      mx = fmaxf(mx, val);
    }
#pragma unroll
    for (int off = 1; off < 16; off <<= 1) mx = fmaxf(mx, __shfl_xor(mx, off));
    float s = 0.f;
#pragma unroll
    for (int j = 0; j < 8; ++j) {
      float e = __expf(acc[j][reg] - mx);
      acc[j][reg] = e; s += e;
    }
#pragma unroll
    for (int off = 1; off < 16; off <<= 1) s += __shfl_xor(s, off);
    s4[reg] = s;   // normalization deferred to the output store
  }

  __syncthreads();   // all waves done reading sK before aliased sP writes
  // ---- P -> LDS (unnormalized), pair-packed b32 on even-col lanes ----
#pragma unroll
  for (int j = 0; j < 8; ++j) {
#pragma unroll
    for (int reg = 0; reg < 4; ++reg) {
      float partner = __shfl_xor(acc[j][reg], 1);
      if ((col & 1) == 0) {
        int r = w * 16 + quad * 4 + reg;
        int phys = r * 128 + ((((2 * j) + (col >> 3)) ^ (r & 15)) << 3) + (col & 7);
        *(unsigned int*)(sP + phys) = pk2(acc[j][reg], partner);
      }
    }
  }
  __syncthreads();

  // ---- O^T = V2^T . P^T via swapped operands ----
  f32x4 oacc[4];
#pragma unroll
  for (int jt = 0; jt < 4; ++jt) oacc[jt] = (f32x4){0.f, 0.f, 0.f, 0.f};
#pragma unroll
  for (int ks = 0; ks < 4; ++ks) {
    int slot = (((ks * 4 + quad) ^ col) << 3);
    bf16x8 ap = *(const bf16x8*)(sP + mrow * 128 + slot);
#pragma unroll
    for (int jt = 0; jt < 4; ++jt) {
      int n = jt * 16 + col;
      bf16x8 bv = *(const bf16x8*)(sVt + n * 128 + slot);
      oacc[jt] = __builtin_amdgcn_mfma_f32_16x16x32_bf16(bv, ap, oacc[jt], 0, 0, 0);
    }
  }

  // ---- fetch 1/s for this lane's q-row (row index = col) ----
  int srcl = (col >> 2) << 4;        // lane holding s for quad' = col>>2
  float sv0 = __shfl(s4[0], srcl);
  float sv1 = __shfl(s4[1], srcl);
  float sv2 = __shfl(s4[2], srcl);
  float sv3 = __shfl(s4[3], srcl);
  float sa = (col & 1) ? sv1 : sv0;
  float sb = (col & 1) ? sv3 : sv2;
  float invR = 1.0f / ((col & 2) ? sb : sa);

  // ---- store: lane owns q-row mrow, channels n = jt*16 + quad*4 + {0..3} ----
  {
    int t = u * 64 + mrow;
    int st = rot ? ((t + 63) & TMASK) : t;
    float* orow = ob + (size_t)st * DH + quad * 4;
#pragma unroll
    for (int jt = 0; jt < 4; ++jt) {
      float4 o4 = make_float4(oacc[jt][0] * invR, oacc[jt][1] * invR,
                              oacc[jt][2] * invR, oacc[jt][3] * invR);
      *(float4*)(orow + jt * 16) = o4;
    }
  }
}

// ---------------------------------------------------------------------------
extern "C" void kernel_launch(void* const* d_in, const int* in_sizes, int n_in,
                              void* d_out, int out_size, void* d_ws, size_t ws_size,
                              hipStream_t stream) {
  const float* q     = (const float*)d_in[0];
  const float* k     = (const float*)d_in[1];
  const float* v     = (const float*)d_in[2];
  const float* sortW = (const float*)d_in[3];
  const float* nullk = (const float*)d_in[4];
  const float* nullv = (const float*)d_in[5];
  float* out = (float*)d_out;

  float* segs     = (float*)d_ws;
  int*   routeIdx = (int*)((char*)d_ws + (size_t)64 * 128 * 64 * 4);
  float* routeP   = (float*)((char*)d_ws + (size_t)64 * 128 * 64 * 4 + 32768);

  seg_sums_kernel<<<512, 256, 0, stream>>>(k, segs);
  route_kernel<<<512, 256, 0, stream>>>(k, sortW, segs, routeIdx, routeP);
  attn_kernel<<<8192, 256, 0, stream>>>(q, k, v, nullk, nullv,
                                        routeIdx, routeP, out);
}